// Round 11
// baseline (114.463 us; speedup 1.0000x reference)
//
#include <hip/hip_runtime.h>
#include <math.h>

#define A0_INV (1.0f/0.529177249f)

typedef __bf16 bf16x8 __attribute__((ext_vector_type(8)));
typedef float  f32x4  __attribute__((ext_vector_type(4)));

__device__ __constant__ float c_SIGMA[8] = {
    0.5515909f, 1.8886297f, 1.3225029f, 1.2316629f,
    2.1884933f, 1.7750372f, 1.3677907f, 1.3820058f};

__device__ __forceinline__ float celu01(float x) {
    return x > 0.0f ? x : 0.1f * (__expf(x * 10.0f) - 1.0f);
}
__device__ __forceinline__ float softplusf_(float x) {
    return fmaxf(x, 0.0f) + log1pf(__expf(-fabsf(x)));
}
__device__ __forceinline__ __bf16 u16_to_bf16(unsigned short u) {
    __bf16 b; __builtin_memcpy(&b, &u, 2); return b;
}
__device__ __forceinline__ unsigned short f_to_bf16_bits(float f) {
    __bf16 b = (__bf16)f; unsigned short u; __builtin_memcpy(&u, &b, 2); return u;
}

// ---- pack weights (K,OUT) f32 -> B-fragment order bf16: Bp[e][nt][kt][lane][8]
__device__ __forceinline__ void pack_one(int idx, const float* __restrict__ W,
                                         __bf16* __restrict__ Bp,
                                         int K, int OUT, int NT, int KT)
{
    int lane = idx & 63;
    int rest = idx >> 6;
    int kt = rest % KT; rest /= KT;
    int nt = rest % NT;
    int e  = rest / NT;
    int col = nt * 16 + (lane & 15);
    int k0  = kt * 32 + (lane >> 4) * 8;
    bf16x8 o;
#pragma unroll
    for (int j = 0; j < 8; ++j) {
        int k = k0 + j;
        float v = (k < K) ? W[((long)e * K + k) * OUT + col] : 0.0f;
        o[j] = (__bf16)v;
    }
    *((bf16x8*)Bp + idx) = o;
}

__global__ __launch_bounds__(256) void pack_all_kernel(
    const float* __restrict__ cW1, const float* __restrict__ cW2, const float* __restrict__ cW3,
    const float* __restrict__ W1,  const float* __restrict__ W2,  const float* __restrict__ W3,
    __bf16* bp_c1, __bf16* bp_c2, __bf16* bp_c3,
    __bf16* bp_e1, __bf16* bp_e2, __bf16* bp_e3)
{
    int idx = blockIdx.x * 256 + threadIdx.x;
    if      (idx <   7680) pack_one(idx,          cW1, bp_c1, 384, 160, 10, 12);
    else if (idx <  10240) pack_one(idx - 7680,   cW2, bp_c2, 160, 128,  8,  5);
    else if (idx <  11776) pack_one(idx - 10240,  cW3, bp_c3, 128,  96,  6,  4);
    else if (idx <  78336) pack_one(idx - 11776,  W1,  bp_e1, 386, 160, 10, 13);
    else if (idx <  98816) pack_one(idx - 78336,  W2,  bp_e2, 160, 128,  8,  5);
    else if (idx < 111104) pack_one(idx - 98816,  W3,  bp_e3, 128,  96,  6,  4);
}

// A-fragment from global fp32 aev, row = atom index
__device__ __forceinline__ bf16x8 loadAf(const float* __restrict__ aev,
                                         int atom, int kt, int g)
{
    const float* p = aev + (long)atom * 384 + kt * 32 + g * 8;
    float4 va = *(const float4*)p, vb = *(const float4*)(p + 4);
    bf16x8 r = {(__bf16)va.x, (__bf16)va.y, (__bf16)va.z, (__bf16)va.w,
                (__bf16)vb.x, (__bf16)vb.y, (__bf16)vb.z, (__bf16)vb.w};
    return r;
}

// ---- 8-wave MLP layer over 64-row LDS tile (uniform B), 1-deep B prefetch
template<int NT, int KT, int INS, int OUTS, bool CELU>
__device__ __forceinline__ void mlp_layer8(const __bf16* sIn, const bf16x8* __restrict__ Bp,
                                           const float* __restrict__ bias, __bf16* sOut, int tid)
{
    const int lane = tid & 63;
    const int wid  = tid >> 6;
    const int mw   = wid >> 2;
    const int nw   = wid & 3;
    const int r16  = lane & 15;
    const int g    = lane >> 4;
    constexpr int NJ = (NT + 3) / 4;
    f32x4 acc[2][NJ];
#pragma unroll
    for (int mi = 0; mi < 2; ++mi)
#pragma unroll
        for (int j = 0; j < NJ; ++j)
            acc[mi][j] = (f32x4){0.f, 0.f, 0.f, 0.f};

    bf16x8 bcur[NJ], bnxt[NJ];
#pragma unroll
    for (int j = 0; j < NJ; ++j) {
        const int nt = nw + 4 * j;
        if (nt < NT) bcur[j] = Bp[(nt * KT) * 64 + lane];
    }
    for (int kt = 0; kt < KT; ++kt) {
        bf16x8 a[2];
#pragma unroll
        for (int mi = 0; mi < 2; ++mi)
            a[mi] = *(const bf16x8*)(sIn + ((mw * 2 + mi) * 16 + r16) * INS + kt * 32 + g * 8);
        if (kt + 1 < KT) {
#pragma unroll
            for (int j = 0; j < NJ; ++j) {
                const int nt = nw + 4 * j;
                if (nt < NT) bnxt[j] = Bp[(nt * KT + kt + 1) * 64 + lane];
            }
        }
#pragma unroll
        for (int j = 0; j < NJ; ++j) {
            const int nt = nw + 4 * j;
            if (nt < NT) {
#pragma unroll
                for (int mi = 0; mi < 2; ++mi)
                    acc[mi][j] = __builtin_amdgcn_mfma_f32_16x16x32_bf16(a[mi], bcur[j], acc[mi][j], 0, 0, 0);
            }
        }
#pragma unroll
        for (int j = 0; j < NJ; ++j) bcur[j] = bnxt[j];
    }
#pragma unroll
    for (int j = 0; j < NJ; ++j) {
        const int nt = nw + 4 * j;
        if (nt < NT) {
            const float bb = bias[nt * 16 + r16];
#pragma unroll
            for (int mi = 0; mi < 2; ++mi)
#pragma unroll
                for (int r = 0; r < 4; ++r) {
                    float v = acc[mi][j][r] + bb;
                    if (CELU) v = celu01(v);
                    sOut[((mw * 2 + mi) * 16 + g * 4 + r) * OUTS + nt * 16 + r16] = (__bf16)v;
                }
        }
    }
}

// ---- 2-wave per-tile MLP layer (16 rows, per-tile expert B), LDS input ----
// nw2 in {0,1}; nt = nw2 + 2*j. Caller guards by tile validity; barriers outside.
template<int NT, int KT, int INS, int OUTS>
__device__ __forceinline__ void mlp_tile2(const __bf16* sIn, const bf16x8* __restrict__ Bp,
                                          const float* __restrict__ bias, __bf16* sOut,
                                          int lane, int nw2)
{
    const int r16 = lane & 15;
    const int g   = lane >> 4;
    constexpr int NJ = NT / 2;
    f32x4 acc[NJ];
#pragma unroll
    for (int j = 0; j < NJ; ++j) acc[j] = (f32x4){0.f, 0.f, 0.f, 0.f};
    bf16x8 bcur[NJ], bnxt[NJ];
#pragma unroll
    for (int j = 0; j < NJ; ++j)
        bcur[j] = Bp[((nw2 + 2 * j) * KT) * 64 + lane];
    for (int kt = 0; kt < KT; ++kt) {
        bf16x8 a = *(const bf16x8*)(sIn + r16 * INS + kt * 32 + g * 8);
        if (kt + 1 < KT) {
#pragma unroll
            for (int j = 0; j < NJ; ++j)
                bnxt[j] = Bp[((nw2 + 2 * j) * KT + kt + 1) * 64 + lane];
        }
#pragma unroll
        for (int j = 0; j < NJ; ++j)
            acc[j] = __builtin_amdgcn_mfma_f32_16x16x32_bf16(a, bcur[j], acc[j], 0, 0, 0);
#pragma unroll
        for (int j = 0; j < NJ; ++j) bcur[j] = bnxt[j];
    }
#pragma unroll
    for (int j = 0; j < NJ; ++j) {
        const int nt = nw2 + 2 * j;
        const float bb = bias[nt * 16 + r16];
#pragma unroll
        for (int r = 0; r < 4; ++r) {
            float v = celu01(acc[j][r] + bb);
            sOut[(g * 4 + r) * OUTS + nt * 16 + r16] = (__bf16)v;
        }
    }
}

// vectorized dot: h[96] bf16 (16B-aligned) . w4[96] f32
__device__ __forceinline__ float l4_dot(const __bf16* __restrict__ h,
                                        const float* __restrict__ w4)
{
    float acc = 0.f;
#pragma unroll
    for (int u8 = 0; u8 < 12; ++u8) {
        bf16x8 hv = *(const bf16x8*)(h + u8 * 8);
        float4 wa = *(const float4*)(w4 + u8 * 8);
        float4 wb = *(const float4*)(w4 + u8 * 8 + 4);
        acc = fmaf((float)hv[0], wa.x, acc);
        acc = fmaf((float)hv[1], wa.y, acc);
        acc = fmaf((float)hv[2], wa.z, acc);
        acc = fmaf((float)hv[3], wa.w, acc);
        acc = fmaf((float)hv[4], wb.x, acc);
        acc = fmaf((float)hv[5], wb.y, acc);
        acc = fmaf((float)hv[6], wb.z, acc);
        acc = fmaf((float)hv[7], wb.w, acc);
    }
    return acc;
}

// ================== fully fused kernel: 1 block = 1 molecule ==================
__global__ __launch_bounds__(512, 4) void fused_kernel(
    const float* __restrict__ aev, const int* __restrict__ species,
    const float* __restrict__ coords, const float* __restrict__ netq,
    const __bf16* __restrict__ bp_c1, const __bf16* __restrict__ bp_c2, const __bf16* __restrict__ bp_c3,
    const float* __restrict__ cb1, const float* __restrict__ cb2, const float* __restrict__ cb3,
    const float* __restrict__ cW4, const float* __restrict__ cb4,
    const __bf16* __restrict__ bp_e1, const __bf16* __restrict__ bp_e2, const __bf16* __restrict__ bp_e3,
    const float* __restrict__ b1, const float* __restrict__ b2, const float* __restrict__ b3,
    const float* __restrict__ W4, const float* __restrict__ b4,
    float* __restrict__ o_species, float* __restrict__ o_q, float* __restrict__ o_energy)
{
    __shared__ __align__(16) unsigned char smem[21504 + 17408];  // region B | region C
    __bf16* Bb = (__bf16*)smem;              // 64 rows, strides 168 / 104 over time
    __bf16* Cc = (__bf16*)(smem + 21504);    // 64 rows, stride 136
    __shared__ float sx[64], sy[64], sz[64], sqv[64], ss2[64];
    __shared__ float sEsp[8][64];
    __shared__ float sChi[64], sOut[64];
    __shared__ float sCoul;
    __shared__ unsigned sQE[64];
    __shared__ int sPerm[192];               // up to 12 tiles x 16 rows
    __shared__ int sTileExpert[12];
    __shared__ int sTileBase[8];
    __shared__ int sCnt[8];
    __shared__ int sNT;
    __shared__ int sSpec[64];

    const int t = threadIdx.x;
    const int m = blockIdx.x;
    const int base = m * 64;
    const int lane = t & 63, wid = t >> 6;
    const int r16 = lane & 15, g = lane >> 4;

    // ---- metadata: species, per-species rank, tile table ----
    if (t >= 64 && t < 256) sPerm[t - 64] = -1;
    int myrank = 0, s_ = -1;
    if (t < 64) {
        s_ = species[base + t];
        sSpec[t] = s_;
        o_species[base + t] = (float)s_;
        unsigned long long mym = 0;
#pragma unroll
        for (int e = 0; e < 8; ++e) {
            unsigned long long bm = __ballot(s_ == e);
            if (t == e) sCnt[e] = (int)__popcll(bm);
            if (s_ == e) mym = bm;
        }
        myrank = (int)__popcll(mym & ((1ull << t) - 1ull));
        if (t == 0) {
            int tb = 0;
            for (int e = 0; e < 8; ++e) {
                sTileBase[e] = tb;
                int tc = (sCnt[e] + 15) >> 4;
                for (int k = 0; k < tc; ++k) sTileExpert[tb + k] = e;
                tb += tc;
            }
            sNT = tb;
        }
    }
    __syncthreads();
    if (t < 64) {
        sOut[t] = 0.f;
        if (s_ >= 0) sPerm[sTileBase[s_] * 16 + myrank] = t;
    }

    // ---- chi L1: A from global aev (fp32->bf16), 2mw x 4nw, NT=10 KT=12 ----
    {
        const int mw = wid >> 2, nw = wid & 3;
        const int rowA0 = base + (mw * 2 + 0) * 16 + r16;
        const int rowA1 = base + (mw * 2 + 1) * 16 + r16;
        const bf16x8* Bp = (const bf16x8*)bp_c1;
        f32x4 acc[2][3];
#pragma unroll
        for (int mi = 0; mi < 2; ++mi)
#pragma unroll
            for (int j = 0; j < 3; ++j) acc[mi][j] = (f32x4){0.f, 0.f, 0.f, 0.f};
        bf16x8 bcur[3], bnxt[3];
#pragma unroll
        for (int j = 0; j < 3; ++j) {
            const int nt = nw + 4 * j;
            if (nt < 10) bcur[j] = Bp[(nt * 12) * 64 + lane];
        }
        bf16x8 a0c = loadAf(aev, rowA0, 0, g);
        bf16x8 a1c = loadAf(aev, rowA1, 0, g);
        for (int kt = 0; kt < 12; ++kt) {
            if (kt + 1 < 12) {
#pragma unroll
                for (int j = 0; j < 3; ++j) {
                    const int nt = nw + 4 * j;
                    if (nt < 10) bnxt[j] = Bp[(nt * 12 + kt + 1) * 64 + lane];
                }
            }
            bf16x8 a0n, a1n;
            if (kt + 1 < 12) {
                a0n = loadAf(aev, rowA0, kt + 1, g);
                a1n = loadAf(aev, rowA1, kt + 1, g);
            }
#pragma unroll
            for (int j = 0; j < 3; ++j) {
                const int nt = nw + 4 * j;
                if (nt < 10) {
                    acc[0][j] = __builtin_amdgcn_mfma_f32_16x16x32_bf16(a0c, bcur[j], acc[0][j], 0, 0, 0);
                    acc[1][j] = __builtin_amdgcn_mfma_f32_16x16x32_bf16(a1c, bcur[j], acc[1][j], 0, 0, 0);
                }
            }
#pragma unroll
            for (int j = 0; j < 3; ++j) bcur[j] = bnxt[j];
            if (kt + 1 < 12) { a0c = a0n; a1c = a1n; }
        }
#pragma unroll
        for (int j = 0; j < 3; ++j) {
            const int nt = nw + 4 * j;
            if (nt < 10) {
                const float bb = cb1[nt * 16 + r16];
#pragma unroll
                for (int mi = 0; mi < 2; ++mi)
#pragma unroll
                    for (int r = 0; r < 4; ++r) {
                        float v = celu01(acc[mi][j][r] + bb);
                        Bb[((mw * 2 + mi) * 16 + g * 4 + r) * 168 + nt * 16 + r16] = (__bf16)v;
                    }
            }
        }
    }
    __syncthreads();
    mlp_layer8<8, 5, 168, 136, true>(Bb, (const bf16x8*)bp_c2, cb2, Cc, t);
    __syncthreads();
    mlp_layer8<6, 4, 136, 104, true>(Cc, (const bf16x8*)bp_c3, cb3, Bb, t);
    __syncthreads();
    if (t < 64) {
        float acc = l4_dot(Bb + t * 104, cW4);
        float chiv = softplusf_(acc + cb4[0]);
        if (s_ == -1) chiv = 0.f;
        sChi[t] = chiv;
    }
    __syncthreads();

    // ---- mol: q / ESP / coulomb (8 groups x 8 pair-iters) ----
    {
        const int j = lane, grp = wid;
        const int atom = base + j;
        int s2 = sSpec[j];
        float pad = (s2 != -1) ? 1.0f : 0.0f;
        float chij = sChi[j];
        float cs = chij, na = pad;
#pragma unroll
        for (int o = 32; o > 0; o >>= 1) {
            cs += __shfl_xor(cs, o);
            na += __shfl_xor(na, o);
        }
        float qc = netq[m];
        float k_net = 1.0f + fabsf(qc) / cs;
        float chi_mean = cs / na;
        float k_p = (qc > 0.0f) ? k_net : 1.0f;
        float k_n = (qc < 0.0f) ? k_net : 1.0f;
        float qj = (-k_n * chij + k_p * chi_mean) * pad;

        float sg = c_SIGMA[s2 < 0 ? 0 : s2];
        float x = coords[atom * 3 + 0], y = coords[atom * 3 + 1], z = coords[atom * 3 + 2];
        if (grp == 0) { sx[j] = x; sy[j] = y; sz[j] = z; sqv[j] = qj; ss2[j] = sg * sg; }
        __syncthreads();

        float s2j = sg * sg;
        float ej = 0.0f;
#pragma unroll
        for (int k = 0; k < 8; ++k) {
            int i = grp * 8 + k;
            if (i == j) continue;
            float dx = sx[i] - x, dy = sy[i] - y, dz = sz[i] - z;
            float d = sqrtf(dx * dx + dy * dy + dz * dz + 1e-16f) * A0_INV;
            float ssum = fmaxf(ss2[i] + s2j, 1e-8f);
            float jij = erff(d * rsqrtf(2.0f * ssum)) / d;
            ej = fmaf(sqv[i], jij, ej);
        }
        sEsp[grp][j] = ej;
        __syncthreads();
        if (grp == 0) {
            float e = ((sEsp[0][j] + sEsp[1][j]) + (sEsp[2][j] + sEsp[3][j]))
                    + ((sEsp[4][j] + sEsp[5][j]) + (sEsp[6][j] + sEsp[7][j]));
            e *= pad;
            float ce = qj * e;
#pragma unroll
            for (int o = 32; o > 0; o >>= 1) ce += __shfl_xor(ce, o);
            if (j == 0) sCoul = 0.5f * ce;
            o_q[atom] = qj;
            sQE[j] = ((unsigned)f_to_bf16_bits(e) << 16) | f_to_bf16_bits(qj);
        }
    }
    __syncthreads();

    // ---- expert passes: species-sorted tiles, 2 waves / tile ----
    const int nT = sNT;
    for (int tp = 0; tp * 4 < nT; ++tp) {
        const int tEnd = min(nT, tp * 4 + 4);
        const int tloc = wid >> 1, nw2 = wid & 1;
        const int tileIdx = tp * 4 + tloc;
        const bool act = tileIdx < tEnd;
        int e_ = 0, aloc = -1;
        if (act) {
            e_ = sTileExpert[tileIdx];
            aloc = sPerm[tileIdx * 16 + r16];
        }
        // L1: NT=10, KT=13 (kt12 = q/esp), A from global
        {
            f32x4 acc[5];
#pragma unroll
            for (int j = 0; j < 5; ++j) acc[j] = (f32x4){0.f, 0.f, 0.f, 0.f};
            if (act) {
                const bf16x8* Bp = (const bf16x8*)bp_e1 + (size_t)e_ * 10 * 13 * 64;
                bf16x8 bcur[5], bnxt[5];
#pragma unroll
                for (int j = 0; j < 5; ++j)
                    bcur[j] = Bp[((nw2 + 2 * j) * 13) * 64 + lane];
                bf16x8 ac = {};
                if (aloc >= 0) ac = loadAf(aev, base + aloc, 0, g);
                for (int kt = 0; kt < 12; ++kt) {
#pragma unroll
                    for (int j = 0; j < 5; ++j)
                        bnxt[j] = Bp[((nw2 + 2 * j) * 13 + kt + 1) * 64 + lane];
                    bf16x8 an = {};
                    if (kt + 1 < 12 && aloc >= 0) an = loadAf(aev, base + aloc, kt + 1, g);
#pragma unroll
                    for (int j = 0; j < 5; ++j)
                        acc[j] = __builtin_amdgcn_mfma_f32_16x16x32_bf16(ac, bcur[j], acc[j], 0, 0, 0);
#pragma unroll
                    for (int j = 0; j < 5; ++j) bcur[j] = bnxt[j];
                    ac = an;
                }
                // kt = 12: q/esp at k=384,385 (g==0 lanes)
                bf16x8 aq = {};
                if (g == 0 && aloc >= 0) {
                    unsigned qe = sQE[aloc];
                    aq[0] = u16_to_bf16((unsigned short)(qe & 0xffff));
                    aq[1] = u16_to_bf16((unsigned short)(qe >> 16));
                }
#pragma unroll
                for (int j = 0; j < 5; ++j)
                    acc[j] = __builtin_amdgcn_mfma_f32_16x16x32_bf16(aq, bcur[j], acc[j], 0, 0, 0);
                // epilogue -> Bb rows tloc*16.., stride 168
#pragma unroll
                for (int j = 0; j < 5; ++j) {
                    const int nt = nw2 + 2 * j;
                    const float bb = b1[e_ * 160 + nt * 16 + r16];
#pragma unroll
                    for (int r = 0; r < 4; ++r) {
                        float v = celu01(acc[j][r] + bb);
                        Bb[(tloc * 16 + g * 4 + r) * 168 + nt * 16 + r16] = (__bf16)v;
                    }
                }
            }
        }
        __syncthreads();
        if (act)
            mlp_tile2<8, 5, 168, 136>(Bb + tloc * 16 * 168,
                                      (const bf16x8*)bp_e2 + (size_t)e_ * 8 * 5 * 64,
                                      b2 + e_ * 128, Cc + tloc * 16 * 136, lane, nw2);
        __syncthreads();
        if (act)
            mlp_tile2<6, 4, 136, 104>(Cc + tloc * 16 * 136,
                                      (const bf16x8*)bp_e3 + (size_t)e_ * 6 * 4 * 64,
                                      b3 + e_ * 96, Bb + tloc * 16 * 104, lane, nw2);
        __syncthreads();
        if (t < 64) {
            int ti = tp * 4 + (t >> 4);
            if (ti < tEnd) {
                int al = sPerm[ti * 16 + (t & 15)];
                if (al >= 0) {
                    int ee = sTileExpert[ti];
                    float acc = l4_dot(Bb + t * 104, W4 + ee * 96);
                    sOut[al] = acc + b4[ee];
                }
            }
        }
        __syncthreads();
    }

    // ---- energy: deterministic reduce ----
    if (t < 64) {
        float v = sOut[t];
#pragma unroll
        for (int o = 32; o > 0; o >>= 1) v += __shfl_xor(v, o);
        if (t == 0) o_energy[m] = v + sCoul;
    }
}

extern "C" void kernel_launch(void* const* d_in, const int* in_sizes, int n_in,
                              void* d_out, int out_size, void* d_ws, size_t ws_size,
                              hipStream_t stream)
{
    const int*   species = (const int*)  d_in[0];
    const float* coords  = (const float*)d_in[1];
    const float* netq    = (const float*)d_in[2];
    const float* aev     = (const float*)d_in[3];
    const float* cW1 = (const float*)d_in[4];
    const float* cb1 = (const float*)d_in[5];
    const float* cW2 = (const float*)d_in[6];
    const float* cb2 = (const float*)d_in[7];
    const float* cW3 = (const float*)d_in[8];
    const float* cb3 = (const float*)d_in[9];
    const float* cW4 = (const float*)d_in[10];
    const float* cb4 = (const float*)d_in[11];
    const float* W1  = (const float*)d_in[12];
    const float* b1  = (const float*)d_in[13];
    const float* W2  = (const float*)d_in[14];
    const float* b2  = (const float*)d_in[15];
    const float* W3  = (const float*)d_in[16];
    const float* b3  = (const float*)d_in[17];
    const float* W4  = (const float*)d_in[18];
    const float* b4  = (const float*)d_in[19];

    const int N = in_sizes[2];          // 512
    const int n = in_sizes[0] / N;      // 64
    const int A = N * n;                // 32768

    // workspace: packed weights only
    uintptr_t p = ((uintptr_t)d_ws + 15) & ~(uintptr_t)15;
    __bf16* bp_c1 = (__bf16*)p; p += (size_t)10 * 12 * 512 * 2;
    __bf16* bp_c2 = (__bf16*)p; p += (size_t)8  * 5  * 512 * 2;
    __bf16* bp_c3 = (__bf16*)p; p += (size_t)6  * 4  * 512 * 2;
    __bf16* bp_e1 = (__bf16*)p; p += (size_t)8 * 10 * 13 * 512 * 2;
    __bf16* bp_e2 = (__bf16*)p; p += (size_t)8 * 8  * 5  * 512 * 2;
    __bf16* bp_e3 = (__bf16*)p; p += (size_t)8 * 6  * 4  * 512 * 2;

    float* o_species = (float*)d_out;        // A elems
    float* o_energy  = o_species + A;        // N elems
    float* o_q       = o_energy + N;         // A elems

    pack_all_kernel<<<(111104 + 255) / 256, 256, 0, stream>>>(
        cW1, cW2, cW3, W1, W2, W3, bp_c1, bp_c2, bp_c3, bp_e1, bp_e2, bp_e3);

    fused_kernel<<<N, 512, 0, stream>>>(
        aev, species, coords, netq,
        bp_c1, bp_c2, bp_c3, cb1, cb2, cb3, cW4, cb4,
        bp_e1, bp_e2, bp_e3, b1, b2, b3, W4, b4,
        o_species, o_q, o_energy);
}

// Round 12
// 113.201 us; speedup vs baseline: 1.0111x; 1.0111x over previous
//
#include <hip/hip_runtime.h>
#include <math.h>

#define A0_INV (1.0f/0.529177249f)

typedef __bf16 bf16x8 __attribute__((ext_vector_type(8)));
typedef float  f32x4  __attribute__((ext_vector_type(4)));

__device__ __constant__ float c_SIGMA[8] = {
    0.5515909f, 1.8886297f, 1.3225029f, 1.2316629f,
    2.1884933f, 1.7750372f, 1.3677907f, 1.3820058f};

__device__ __forceinline__ float celu01(float x) {
    return x > 0.0f ? x : 0.1f * (__expf(x * 10.0f) - 1.0f);
}
__device__ __forceinline__ float softplusf_(float x) {
    return fmaxf(x, 0.0f) + log1pf(__expf(-fabsf(x)));
}
__device__ __forceinline__ __bf16 u16_to_bf16(unsigned short u) {
    __bf16 b; __builtin_memcpy(&b, &u, 2); return b;
}
__device__ __forceinline__ unsigned short f_to_bf16_bits(float f) {
    __bf16 b = (__bf16)f; unsigned short u; __builtin_memcpy(&u, &b, 2); return u;
}

// ---- pack weights (K,OUT) f32 -> B-fragment order bf16: Bp[e][nt][kt][lane][8]
__device__ __forceinline__ void pack_one(int idx, const float* __restrict__ W,
                                         __bf16* __restrict__ Bp,
                                         int K, int OUT, int NT, int KT)
{
    int lane = idx & 63;
    int rest = idx >> 6;
    int kt = rest % KT; rest /= KT;
    int nt = rest % NT;
    int e  = rest / NT;
    int col = nt * 16 + (lane & 15);
    int k0  = kt * 32 + (lane >> 4) * 8;
    bf16x8 o;
#pragma unroll
    for (int j = 0; j < 8; ++j) {
        int k = k0 + j;
        float v = (k < K) ? W[((long)e * K + k) * OUT + col] : 0.0f;
        o[j] = (__bf16)v;
    }
    *((bf16x8*)Bp + idx) = o;
}

__global__ __launch_bounds__(256) void pack_all_kernel(
    const float* __restrict__ cW1, const float* __restrict__ cW2, const float* __restrict__ cW3,
    const float* __restrict__ W1,  const float* __restrict__ W2,  const float* __restrict__ W3,
    __bf16* bp_c1, __bf16* bp_c2, __bf16* bp_c3,
    __bf16* bp_e1, __bf16* bp_e2, __bf16* bp_e3)
{
    int idx = blockIdx.x * 256 + threadIdx.x;
    if      (idx <   7680) pack_one(idx,          cW1, bp_c1, 384, 160, 10, 12);
    else if (idx <  10240) pack_one(idx - 7680,   cW2, bp_c2, 160, 128,  8,  5);
    else if (idx <  11776) pack_one(idx - 10240,  cW3, bp_c3, 128,  96,  6,  4);
    else if (idx <  78336) pack_one(idx - 11776,  W1,  bp_e1, 386, 160, 10, 13);
    else if (idx <  98816) pack_one(idx - 78336,  W2,  bp_e2, 160, 128,  8,  5);
    else if (idx < 111104) pack_one(idx - 98816,  W3,  bp_e3, 128,  96,  6,  4);
}

// A-fragment from global fp32 aev, row = atom index
__device__ __forceinline__ bf16x8 loadAf(const float* __restrict__ aev,
                                         int atom, int kt, int g)
{
    const float* p = aev + (long)atom * 384 + kt * 32 + g * 8;
    float4 va = *(const float4*)p, vb = *(const float4*)(p + 4);
    bf16x8 r = {(__bf16)va.x, (__bf16)va.y, (__bf16)va.z, (__bf16)va.w,
                (__bf16)vb.x, (__bf16)vb.y, (__bf16)vb.z, (__bf16)vb.w};
    return r;
}

// ---- 8-wave MLP layer over 64-row LDS tile (uniform B), 1-deep B prefetch
template<int NT, int KT, int INS, int OUTS, bool CELU>
__device__ __forceinline__ void mlp_layer8(const __bf16* sIn, const bf16x8* __restrict__ Bp,
                                           const float* __restrict__ bias, __bf16* sOut, int tid)
{
    const int lane = tid & 63;
    const int wid  = tid >> 6;
    const int mw   = wid >> 2;
    const int nw   = wid & 3;
    const int r16  = lane & 15;
    const int g    = lane >> 4;
    constexpr int NJ = (NT + 3) / 4;
    f32x4 acc[2][NJ];
#pragma unroll
    for (int mi = 0; mi < 2; ++mi)
#pragma unroll
        for (int j = 0; j < NJ; ++j)
            acc[mi][j] = (f32x4){0.f, 0.f, 0.f, 0.f};

    bf16x8 bcur[NJ], bnxt[NJ];
#pragma unroll
    for (int j = 0; j < NJ; ++j) {
        const int nt = nw + 4 * j;
        if (nt < NT) bcur[j] = Bp[(nt * KT) * 64 + lane];
    }
    for (int kt = 0; kt < KT; ++kt) {
        bf16x8 a[2];
#pragma unroll
        for (int mi = 0; mi < 2; ++mi)
            a[mi] = *(const bf16x8*)(sIn + ((mw * 2 + mi) * 16 + r16) * INS + kt * 32 + g * 8);
        if (kt + 1 < KT) {
#pragma unroll
            for (int j = 0; j < NJ; ++j) {
                const int nt = nw + 4 * j;
                if (nt < NT) bnxt[j] = Bp[(nt * KT + kt + 1) * 64 + lane];
            }
        }
#pragma unroll
        for (int j = 0; j < NJ; ++j) {
            const int nt = nw + 4 * j;
            if (nt < NT) {
#pragma unroll
                for (int mi = 0; mi < 2; ++mi)
                    acc[mi][j] = __builtin_amdgcn_mfma_f32_16x16x32_bf16(a[mi], bcur[j], acc[mi][j], 0, 0, 0);
            }
        }
#pragma unroll
        for (int j = 0; j < NJ; ++j) bcur[j] = bnxt[j];
    }
#pragma unroll
    for (int j = 0; j < NJ; ++j) {
        const int nt = nw + 4 * j;
        if (nt < NT) {
            const float bb = bias[nt * 16 + r16];
#pragma unroll
            for (int mi = 0; mi < 2; ++mi)
#pragma unroll
                for (int r = 0; r < 4; ++r) {
                    float v = acc[mi][j][r] + bb;
                    if (CELU) v = celu01(v);
                    sOut[((mw * 2 + mi) * 16 + g * 4 + r) * OUTS + nt * 16 + r16] = (__bf16)v;
                }
        }
    }
}

// ---- 4-wave per-tile MLP layer (16 rows, per-tile expert B), NJ<=2 -------
template<int NT, int KT, int INS, int OUTS>
__device__ __forceinline__ void mlp_tile4(const __bf16* sIn, const bf16x8* __restrict__ Bp,
                                          const float* __restrict__ bias, __bf16* sOut,
                                          int lane, int nw4)
{
    const int r16 = lane & 15;
    const int g   = lane >> 4;
    constexpr int NJ = (NT + 3) / 4;
    f32x4 acc[NJ];
#pragma unroll
    for (int j = 0; j < NJ; ++j) acc[j] = (f32x4){0.f, 0.f, 0.f, 0.f};
    bf16x8 bcur[NJ], bnxt[NJ];
#pragma unroll
    for (int j = 0; j < NJ; ++j) {
        const int nt = nw4 + 4 * j;
        if (nt < NT) bcur[j] = Bp[(nt * KT) * 64 + lane];
    }
    for (int kt = 0; kt < KT; ++kt) {
        bf16x8 a = *(const bf16x8*)(sIn + r16 * INS + kt * 32 + g * 8);
        if (kt + 1 < KT) {
#pragma unroll
            for (int j = 0; j < NJ; ++j) {
                const int nt = nw4 + 4 * j;
                if (nt < NT) bnxt[j] = Bp[(nt * KT + kt + 1) * 64 + lane];
            }
        }
#pragma unroll
        for (int j = 0; j < NJ; ++j) {
            const int nt = nw4 + 4 * j;
            if (nt < NT)
                acc[j] = __builtin_amdgcn_mfma_f32_16x16x32_bf16(a, bcur[j], acc[j], 0, 0, 0);
        }
#pragma unroll
        for (int j = 0; j < NJ; ++j) bcur[j] = bnxt[j];
    }
#pragma unroll
    for (int j = 0; j < NJ; ++j) {
        const int nt = nw4 + 4 * j;
        if (nt < NT) {
            const float bb = bias[nt * 16 + r16];
#pragma unroll
            for (int r = 0; r < 4; ++r) {
                float v = celu01(acc[j][r] + bb);
                sOut[(g * 4 + r) * OUTS + nt * 16 + r16] = (__bf16)v;
            }
        }
    }
}

// vectorized dot: h[96] bf16 (16B-aligned) . w4[96] f32
__device__ __forceinline__ float l4_dot(const __bf16* __restrict__ h,
                                        const float* __restrict__ w4)
{
    float acc = 0.f;
#pragma unroll
    for (int u8 = 0; u8 < 12; ++u8) {
        bf16x8 hv = *(const bf16x8*)(h + u8 * 8);
        float4 wa = *(const float4*)(w4 + u8 * 8);
        float4 wb = *(const float4*)(w4 + u8 * 8 + 4);
        acc = fmaf((float)hv[0], wa.x, acc);
        acc = fmaf((float)hv[1], wa.y, acc);
        acc = fmaf((float)hv[2], wa.z, acc);
        acc = fmaf((float)hv[3], wa.w, acc);
        acc = fmaf((float)hv[4], wb.x, acc);
        acc = fmaf((float)hv[5], wb.y, acc);
        acc = fmaf((float)hv[6], wb.z, acc);
        acc = fmaf((float)hv[7], wb.w, acc);
    }
    return acc;
}

// ================== fully fused kernel: 1 block = 1 molecule ==================
__global__ __launch_bounds__(512, 4) void fused_kernel(
    const float* __restrict__ aev, const int* __restrict__ species,
    const float* __restrict__ coords, const float* __restrict__ netq,
    const __bf16* __restrict__ bp_c1, const __bf16* __restrict__ bp_c2, const __bf16* __restrict__ bp_c3,
    const float* __restrict__ cb1, const float* __restrict__ cb2, const float* __restrict__ cb3,
    const float* __restrict__ cW4, const float* __restrict__ cb4,
    const __bf16* __restrict__ bp_e1, const __bf16* __restrict__ bp_e2, const __bf16* __restrict__ bp_e3,
    const float* __restrict__ b1, const float* __restrict__ b2, const float* __restrict__ b3,
    const float* __restrict__ W4, const float* __restrict__ b4,
    float* __restrict__ o_species, float* __restrict__ o_q, float* __restrict__ o_energy)
{
    __shared__ __align__(16) unsigned char smem[21504 + 17408];  // region B | region C
    __bf16* Bb = (__bf16*)smem;              // 64 rows (chi) / 32 rows (expert)
    __bf16* Cc = (__bf16*)(smem + 21504);
    __shared__ float sx[64], sy[64], sz[64], sqv[64], ss2[64];
    __shared__ float sEsp[8][64];
    __shared__ float sChi[64], sOut[64];
    __shared__ float sCoul;
    __shared__ unsigned sQE[64];
    __shared__ int sPerm[192];               // up to 12 tiles x 16 rows
    __shared__ int sTileExpert[12];
    __shared__ int sTileBase[8];
    __shared__ int sCnt[8];
    __shared__ int sNT;
    __shared__ int sSpec[64];

    const int t = threadIdx.x;
    const int m = blockIdx.x;
    const int base = m * 64;
    const int lane = t & 63, wid = t >> 6;
    const int r16 = lane & 15, g = lane >> 4;

    // ---- metadata: species, per-species rank, tile table ----
    if (t >= 64 && t < 256) sPerm[t - 64] = -1;
    int myrank = 0, s_ = -1;
    if (t < 64) {
        s_ = species[base + t];
        sSpec[t] = s_;
        o_species[base + t] = (float)s_;
        unsigned long long mym = 0;
#pragma unroll
        for (int e = 0; e < 8; ++e) {
            unsigned long long bm = __ballot(s_ == e);
            if (t == e) sCnt[e] = (int)__popcll(bm);
            if (s_ == e) mym = bm;
        }
        myrank = (int)__popcll(mym & ((1ull << t) - 1ull));
        if (t == 0) {
            int tb = 0;
            for (int e = 0; e < 8; ++e) {
                sTileBase[e] = tb;
                int tc = (sCnt[e] + 15) >> 4;
                for (int k = 0; k < tc; ++k) sTileExpert[tb + k] = e;
                tb += tc;
            }
            sNT = tb;
        }
    }
    __syncthreads();
    if (t < 64) {
        sOut[t] = 0.f;
        if (s_ >= 0) sPerm[sTileBase[s_] * 16 + myrank] = t;
    }

    // ---- chi L1: A from global aev (fp32->bf16), 2mw x 4nw, NT=10 KT=12 ----
    {
        const int mw = wid >> 2, nw = wid & 3;
        const int rowA0 = base + (mw * 2 + 0) * 16 + r16;
        const int rowA1 = base + (mw * 2 + 1) * 16 + r16;
        const bf16x8* Bp = (const bf16x8*)bp_c1;
        f32x4 acc[2][3];
#pragma unroll
        for (int mi = 0; mi < 2; ++mi)
#pragma unroll
            for (int j = 0; j < 3; ++j) acc[mi][j] = (f32x4){0.f, 0.f, 0.f, 0.f};
        bf16x8 bcur[3], bnxt[3];
#pragma unroll
        for (int j = 0; j < 3; ++j) {
            const int nt = nw + 4 * j;
            if (nt < 10) bcur[j] = Bp[(nt * 12) * 64 + lane];
        }
        bf16x8 a0c = loadAf(aev, rowA0, 0, g);
        bf16x8 a1c = loadAf(aev, rowA1, 0, g);
        for (int kt = 0; kt < 12; ++kt) {
            if (kt + 1 < 12) {
#pragma unroll
                for (int j = 0; j < 3; ++j) {
                    const int nt = nw + 4 * j;
                    if (nt < 10) bnxt[j] = Bp[(nt * 12 + kt + 1) * 64 + lane];
                }
            }
            bf16x8 a0n, a1n;
            if (kt + 1 < 12) {
                a0n = loadAf(aev, rowA0, kt + 1, g);
                a1n = loadAf(aev, rowA1, kt + 1, g);
            }
#pragma unroll
            for (int j = 0; j < 3; ++j) {
                const int nt = nw + 4 * j;
                if (nt < 10) {
                    acc[0][j] = __builtin_amdgcn_mfma_f32_16x16x32_bf16(a0c, bcur[j], acc[0][j], 0, 0, 0);
                    acc[1][j] = __builtin_amdgcn_mfma_f32_16x16x32_bf16(a1c, bcur[j], acc[1][j], 0, 0, 0);
                }
            }
#pragma unroll
            for (int j = 0; j < 3; ++j) bcur[j] = bnxt[j];
            if (kt + 1 < 12) { a0c = a0n; a1c = a1n; }
        }
#pragma unroll
        for (int j = 0; j < 3; ++j) {
            const int nt = nw + 4 * j;
            if (nt < 10) {
                const float bb = cb1[nt * 16 + r16];
#pragma unroll
                for (int mi = 0; mi < 2; ++mi)
#pragma unroll
                    for (int r = 0; r < 4; ++r) {
                        float v = celu01(acc[mi][j][r] + bb);
                        Bb[((mw * 2 + mi) * 16 + g * 4 + r) * 168 + nt * 16 + r16] = (__bf16)v;
                    }
            }
        }
    }
    __syncthreads();
    mlp_layer8<8, 5, 168, 136, true>(Bb, (const bf16x8*)bp_c2, cb2, Cc, t);
    __syncthreads();
    mlp_layer8<6, 4, 136, 104, true>(Cc, (const bf16x8*)bp_c3, cb3, Bb, t);
    __syncthreads();
    if (t < 64) {
        float acc = l4_dot(Bb + t * 104, cW4);
        float chiv = softplusf_(acc + cb4[0]);
        if (s_ == -1) chiv = 0.f;
        sChi[t] = chiv;
    }
    __syncthreads();

    // ---- mol: q / ESP / coulomb (8 groups x 8 pair-iters) ----
    {
        const int j = lane, grp = wid;
        const int atom = base + j;
        int s2 = sSpec[j];
        float pad = (s2 != -1) ? 1.0f : 0.0f;
        float chij = sChi[j];
        float cs = chij, na = pad;
#pragma unroll
        for (int o = 32; o > 0; o >>= 1) {
            cs += __shfl_xor(cs, o);
            na += __shfl_xor(na, o);
        }
        float qc = netq[m];
        float k_net = 1.0f + fabsf(qc) / cs;
        float chi_mean = cs / na;
        float k_p = (qc > 0.0f) ? k_net : 1.0f;
        float k_n = (qc < 0.0f) ? k_net : 1.0f;
        float qj = (-k_n * chij + k_p * chi_mean) * pad;

        float sg = c_SIGMA[s2 < 0 ? 0 : s2];
        float x = coords[atom * 3 + 0], y = coords[atom * 3 + 1], z = coords[atom * 3 + 2];
        if (grp == 0) { sx[j] = x; sy[j] = y; sz[j] = z; sqv[j] = qj; ss2[j] = sg * sg; }
        __syncthreads();

        float s2j = sg * sg;
        float ej = 0.0f;
#pragma unroll
        for (int k = 0; k < 8; ++k) {
            int i = grp * 8 + k;
            if (i == j) continue;
            float dx = sx[i] - x, dy = sy[i] - y, dz = sz[i] - z;
            float d = sqrtf(dx * dx + dy * dy + dz * dz + 1e-16f) * A0_INV;
            float ssum = fmaxf(ss2[i] + s2j, 1e-8f);
            float jij = erff(d * rsqrtf(2.0f * ssum)) / d;
            ej = fmaf(sqv[i], jij, ej);
        }
        sEsp[grp][j] = ej;
        __syncthreads();
        if (grp == 0) {
            float e = ((sEsp[0][j] + sEsp[1][j]) + (sEsp[2][j] + sEsp[3][j]))
                    + ((sEsp[4][j] + sEsp[5][j]) + (sEsp[6][j] + sEsp[7][j]));
            e *= pad;
            float ce = qj * e;
#pragma unroll
            for (int o = 32; o > 0; o >>= 1) ce += __shfl_xor(ce, o);
            if (j == 0) sCoul = 0.5f * ce;
            o_q[atom] = qj;
            sQE[j] = ((unsigned)f_to_bf16_bits(e) << 16) | f_to_bf16_bits(qj);
        }
    }
    __syncthreads();

    // ---- expert passes: species-sorted tiles, 2 tiles/pass x 4 waves/tile ----
    const int nT = sNT;
    for (int tp = 0; tp * 2 < nT; ++tp) {
        const int tloc = wid >> 2;          // 0..1
        const int nw4  = wid & 3;           // 0..3
        const int tileIdx = tp * 2 + tloc;
        const bool act = tileIdx < nT;
        int e_ = 0, aloc = -1;
        if (act) {
            e_ = sTileExpert[tileIdx];
            aloc = sPerm[tileIdx * 16 + r16];
        }
        // L1: NT=10, KT=13 (kt12 = q/esp), NJ=3, A from global
        if (act) {
            const bf16x8* Bp = (const bf16x8*)bp_e1 + (size_t)e_ * 10 * 13 * 64;
            f32x4 acc[3];
#pragma unroll
            for (int j = 0; j < 3; ++j) acc[j] = (f32x4){0.f, 0.f, 0.f, 0.f};
            bf16x8 bcur[3], bnxt[3];
#pragma unroll
            for (int j = 0; j < 3; ++j) {
                const int nt = nw4 + 4 * j;
                if (nt < 10) bcur[j] = Bp[(nt * 13) * 64 + lane];
            }
            bf16x8 ac = {};
            if (aloc >= 0) ac = loadAf(aev, base + aloc, 0, g);
            for (int kt = 0; kt < 12; ++kt) {
#pragma unroll
                for (int j = 0; j < 3; ++j) {
                    const int nt = nw4 + 4 * j;
                    if (nt < 10) bnxt[j] = Bp[(nt * 13 + kt + 1) * 64 + lane];
                }
                bf16x8 an = {};
                if (kt + 1 < 12 && aloc >= 0) an = loadAf(aev, base + aloc, kt + 1, g);
#pragma unroll
                for (int j = 0; j < 3; ++j) {
                    const int nt = nw4 + 4 * j;
                    if (nt < 10)
                        acc[j] = __builtin_amdgcn_mfma_f32_16x16x32_bf16(ac, bcur[j], acc[j], 0, 0, 0);
                }
#pragma unroll
                for (int j = 0; j < 3; ++j) bcur[j] = bnxt[j];
                if (kt + 1 < 12) ac = an;
            }
            // kt = 12: q/esp at k=384,385 (g==0 lanes)
            bf16x8 aq = {};
            if (g == 0 && aloc >= 0) {
                unsigned qe = sQE[aloc];
                aq[0] = u16_to_bf16((unsigned short)(qe & 0xffff));
                aq[1] = u16_to_bf16((unsigned short)(qe >> 16));
            }
#pragma unroll
            for (int j = 0; j < 3; ++j) {
                const int nt = nw4 + 4 * j;
                if (nt < 10)
                    acc[j] = __builtin_amdgcn_mfma_f32_16x16x32_bf16(aq, bcur[j], acc[j], 0, 0, 0);
            }
            // epilogue -> Bb rows tloc*16.., stride 168
#pragma unroll
            for (int j = 0; j < 3; ++j) {
                const int nt = nw4 + 4 * j;
                if (nt < 10) {
                    const float bb = b1[e_ * 160 + nt * 16 + r16];
#pragma unroll
                    for (int r = 0; r < 4; ++r) {
                        float v = celu01(acc[j][r] + bb);
                        Bb[(tloc * 16 + g * 4 + r) * 168 + nt * 16 + r16] = (__bf16)v;
                    }
                }
            }
        }
        __syncthreads();
        if (act)
            mlp_tile4<8, 5, 168, 136>(Bb + tloc * 16 * 168,
                                      (const bf16x8*)bp_e2 + (size_t)e_ * 8 * 5 * 64,
                                      b2 + e_ * 128, Cc + tloc * 16 * 136, lane, nw4);
        __syncthreads();
        if (act)
            mlp_tile4<6, 4, 136, 104>(Cc + tloc * 16 * 136,
                                      (const bf16x8*)bp_e3 + (size_t)e_ * 6 * 4 * 64,
                                      b3 + e_ * 96, Bb + tloc * 16 * 104, lane, nw4);
        __syncthreads();
        if (t < 32) {
            int ti = tp * 2 + (t >> 4);
            if (ti < nT) {
                int al = sPerm[ti * 16 + (t & 15)];
                if (al >= 0) {
                    int ee = sTileExpert[ti];
                    float acc = l4_dot(Bb + t * 104, W4 + ee * 96);
                    sOut[al] = acc + b4[ee];
                }
            }
        }
        __syncthreads();
    }

    // ---- energy: deterministic reduce ----
    if (t < 64) {
        float v = sOut[t];
#pragma unroll
        for (int o = 32; o > 0; o >>= 1) v += __shfl_xor(v, o);
        if (t == 0) o_energy[m] = v + sCoul;
    }
}

extern "C" void kernel_launch(void* const* d_in, const int* in_sizes, int n_in,
                              void* d_out, int out_size, void* d_ws, size_t ws_size,
                              hipStream_t stream)
{
    const int*   species = (const int*)  d_in[0];
    const float* coords  = (const float*)d_in[1];
    const float* netq    = (const float*)d_in[2];
    const float* aev     = (const float*)d_in[3];
    const float* cW1 = (const float*)d_in[4];
    const float* cb1 = (const float*)d_in[5];
    const float* cW2 = (const float*)d_in[6];
    const float* cb2 = (const float*)d_in[7];
    const float* cW3 = (const float*)d_in[8];
    const float* cb3 = (const float*)d_in[9];
    const float* cW4 = (const float*)d_in[10];
    const float* cb4 = (const float*)d_in[11];
    const float* W1  = (const float*)d_in[12];
    const float* b1  = (const float*)d_in[13];
    const float* W2  = (const float*)d_in[14];
    const float* b2  = (const float*)d_in[15];
    const float* W3  = (const float*)d_in[16];
    const float* b3  = (const float*)d_in[17];
    const float* W4  = (const float*)d_in[18];
    const float* b4  = (const float*)d_in[19];

    const int N = in_sizes[2];          // 512
    const int n = in_sizes[0] / N;      // 64
    const int A = N * n;                // 32768

    // workspace: packed weights only
    uintptr_t p = ((uintptr_t)d_ws + 15) & ~(uintptr_t)15;
    __bf16* bp_c1 = (__bf16*)p; p += (size_t)10 * 12 * 512 * 2;
    __bf16* bp_c2 = (__bf16*)p; p += (size_t)8  * 5  * 512 * 2;
    __bf16* bp_c3 = (__bf16*)p; p += (size_t)6  * 4  * 512 * 2;
    __bf16* bp_e1 = (__bf16*)p; p += (size_t)8 * 10 * 13 * 512 * 2;
    __bf16* bp_e2 = (__bf16*)p; p += (size_t)8 * 8  * 5  * 512 * 2;
    __bf16* bp_e3 = (__bf16*)p; p += (size_t)8 * 6  * 4  * 512 * 2;

    float* o_species = (float*)d_out;        // A elems
    float* o_energy  = o_species + A;        // N elems
    float* o_q       = o_energy + N;         // A elems

    pack_all_kernel<<<(111104 + 255) / 256, 256, 0, stream>>>(
        cW1, cW2, cW3, W1, W2, W3, bp_c1, bp_c2, bp_c3, bp_e1, bp_e2, bp_e3);

    fused_kernel<<<N, 512, 0, stream>>>(
        aev, species, coords, netq,
        bp_c1, bp_c2, bp_c3, cb1, cb2, cb3, cW4, cb4,
        bp_e1, bp_e2, bp_e3, b1, b2, b3, W4, b4,
        o_species, o_q, o_energy);
}